// Round 1
// baseline (381.895 us; speedup 1.0000x reference)
//
#include <hip/hip_runtime.h>
#include <hip/hip_bf16.h>
#include <math.h>

// Problem constants
#define N_  2
#define H_  8
#define G_  16      // N_*H_
#define L_  1024
#define S_  1024
#define E_  64
#define NC_ 6

typedef __attribute__((ext_vector_type(4))) float floatx4;
typedef __attribute__((ext_vector_type(8))) short short8;

#define MFMA16 __builtin_amdgcn_mfma_f32_16x16x32_bf16

// ---------------- workspace layout (bytes) ----------------
// Ahat: [c][g][l][128] bf16  (hi 0..63 | lo 64..127)
#define AHAT_OFF   0
#define AHAT_BYTES (NC_*G_*L_*128*2)          // 25,165,824
#define KHAT_OFF   (AHAT_OFF + AHAT_BYTES)
#define KHAT_BYTES (G_*S_*128*2)              //  4,194,304
#define PI_OFF     (KHAT_OFF + KHAT_BYTES)    // pi_t: [c][g][l] f32
#define PI_BYTES   (NC_*G_*L_*4)
#define HSQ_OFF    (PI_OFF + PI_BYTES)        // hsq: [c][g][l] f32
#define HSQ_BYTES  (NC_*G_*L_*4)
#define KSQ_OFF    (HSQ_OFF + HSQ_BYTES)      // ksq: [g][s] f32
#define KSQ_BYTES  (G_*S_*4)
#define SM_OFF     (KSQ_OFF + KSQ_BYTES)      // stats m: [c][g][l]
#define SM_BYTES   (NC_*G_*L_*4)
#define SZ_OFF     (SM_OFF + SM_BYTES)        // stats z: [c][g][l]
#define SZ_BYTES   (NC_*G_*L_*4)
// total ~30.99 MB

// Shared logit function: MUST be bit-identical between k_stats and k_emit.
__device__ __forceinline__ float logit_rt(int c, float d, float hq, float kq) {
  if (c == 0) return d;                               // L
  if (c == 3) { float tt = d + 1.0f; return tt*tt; }  // Y
  float ns = hq + kq - 2.0f*d;
  if (c == 1) return -__logf(1.0f + ns);              // O
  if (c == 2) return -ns;                             // P
  if (c == 4) return __expf(-0.5f*ns);                // R
  return __cosf(ns) * __expf(-ns);                    // W
}

// ---------------------------------------------------------------------------
// K1a: per (n,h,l-chunk of 32): pi (softmax over 6), htilde=tanh(q@C[c,h])
// split to bf16 hi/lo, and |htilde|^2.
// grid 512 blocks (n*8*32), 256 threads. Dyn LDS = 59,360 B.
// ---------------------------------------------------------------------------
__global__ __launch_bounds__(256) void k_prep_a(
    const float* __restrict__ q, const float* __restrict__ M,
    const float* __restrict__ C, __hip_bfloat16* __restrict__ Ahat,
    float* __restrict__ pi_t, float* __restrict__ hsq) {
  extern __shared__ char smraw[];
  float* qs    = (float*)smraw;          // [32][65]   (pad 65: bank spread)
  float* Cs    = qs + 32*65;             // [3][4104]  (pad: bank stagger)
  float* hsq_s = Cs + 3*4104;            // [6][32]
  float* pm    = hsq_s + 6*32;           // [32][8]

  int b  = blockIdx.x;
  int n  = b >> 8; int h = (b >> 5) & 7; int lc = b & 31;
  int l0 = lc * 32; int g = n*8 + h;
  int t  = threadIdx.x;

  if (t < 192) hsq_s[t] = 0.0f;
  // stage q rows: 32 rows x 16 float4 segs
  {
    int u = t;
    #pragma unroll
    for (int rep = 0; rep < 2; rep++, u += 256) {
      int row = u >> 4, seg = u & 15;
      float4 v = *(const float4*)(q + (((size_t)(n*L_ + l0 + row))*H_ + h)*E_ + seg*4);
      float* dst = qs + row*65 + seg*4;
      dst[0]=v.x; dst[1]=v.y; dst[2]=v.z; dst[3]=v.w;
    }
  }
  for (int gc = 0; gc < 2; gc++) {
    __syncthreads();   // hsq_s init / previous pass reads complete
    for (int u = t; u < 3072; u += 256) {   // 3 codes x 64e x 16 segs
      int cc = u >> 10; int rem = u & 1023; int e = rem >> 4; int seg = rem & 15;
      float4 v = *(const float4*)(C + (((size_t)((gc*3+cc)*8 + h))*64 + e)*64 + seg*4);
      float* dst = Cs + cc*4104 + e*64 + seg*4;
      dst[0]=v.x; dst[1]=v.y; dst[2]=v.z; dst[3]=v.w;
    }
    __syncthreads();
    if (t < 192) {
      int cc = t >> 6; int tt = t & 63; int lg = tt >> 3; int fg = tt & 7;
      int c = gc*3 + cc;
      float acc[4][8];
      #pragma unroll
      for (int i = 0; i < 4; i++)
        #pragma unroll
        for (int j = 0; j < 8; j++) acc[i][j] = 0.0f;
      for (int e = 0; e < 64; e++) {
        float c8[8];
        #pragma unroll
        for (int j = 0; j < 8; j++) c8[j] = Cs[cc*4104 + e*64 + fg*8 + j];
        #pragma unroll
        for (int i = 0; i < 4; i++) {
          float qv = qs[(lg*4+i)*65 + e];
          #pragma unroll
          for (int j = 0; j < 8; j++) acc[i][j] = fmaf(qv, c8[j], acc[i][j]);
        }
      }
      #pragma unroll
      for (int i = 0; i < 4; i++) {
        int l = l0 + lg*4 + i;
        size_t rowb = (((size_t)(c*G_ + g))*L_ + l) * 128;
        float ss = 0.0f;
        #pragma unroll
        for (int j = 0; j < 8; j++) {
          float hv = tanhf(acc[i][j]);
          ss += hv*hv;
          __hip_bfloat16 hi = __float2bfloat16(hv);
          __hip_bfloat16 lo = __float2bfloat16(hv - __bfloat162float(hi));
          Ahat[rowb + fg*8 + j]      = hi;
          Ahat[rowb + 64 + fg*8 + j] = lo;
        }
        atomicAdd(&hsq_s[c*32 + lg*4 + i], ss);
      }
    }
  }
  // pi: logits q@M then softmax over k (6)
  if (t < 192) {
    int k = t >> 5; int l = t & 31;
    float p = 0.0f;
    for (int e = 0; e < 64; e++) p += qs[l*65 + e] * M[(h*64 + e)*6 + k];
    pm[l*8 + k] = p;
  }
  __syncthreads();   // pm ready; also all hsq_s atomics done
  if (t < 192) {
    int k = t >> 5; int l = t & 31;
    float mx = pm[l*8+0];
    #pragma unroll
    for (int kk = 1; kk < 6; kk++) mx = fmaxf(mx, pm[l*8+kk]);
    float den = 0.0f;
    #pragma unroll
    for (int kk = 0; kk < 6; kk++) den += __expf(pm[l*8+kk] - mx);
    float pv = __expf(pm[l*8+k] - mx) / den;
    size_t idx = ((size_t)(k*G_ + g))*L_ + l0 + l;
    pi_t[idx] = pv;
    hsq[idx]  = hsq_s[k*32 + l];
  }
}

// ---------------------------------------------------------------------------
// K1b: key split hi/lo + ksq. grid 4096 x 256 (wave per (g,s) row).
// ---------------------------------------------------------------------------
__global__ __launch_bounds__(256) void k_prep_k(
    const float* __restrict__ key, __hip_bfloat16* __restrict__ Khat,
    float* __restrict__ ksq) {
  int t = threadIdx.x; int wv = t >> 6; int lane = t & 63;
  int r = blockIdx.x*4 + wv;
  int g = r >> 10; int s = r & 1023; int n = g >> 3; int h = g & 7;
  float v = key[(((size_t)(n*S_ + s))*H_ + h)*E_ + lane];
  __hip_bfloat16 hi = __float2bfloat16(v);
  __hip_bfloat16 lo = __float2bfloat16(v - __bfloat162float(hi));
  size_t base = ((size_t)g*S_ + s)*128;
  Khat[base + lane]      = hi;
  Khat[base + 64 + lane] = lo;
  float sq = v*v;
  #pragma unroll
  for (int off = 32; off; off >>= 1) sq += __shfl_xor(sq, off);
  if (lane == 0) ksq[(size_t)g*S_ + s] = sq;
}

// ---------------------------------------------------------------------------
// K2: stats pass. grid (64 ltiles, 16 g, 6 c), 256 thr (4 waves).
// Each block: 16 l-rows, sweep 16 s-tiles of 64. Wave w owns 16-col tile w.
// Online per-lane (m,Z); butterfly + LDS merge at end. Dyn LDS = 26,688 B.
// ---------------------------------------------------------------------------
__global__ __launch_bounds__(256) void k_stats(
    const __hip_bfloat16* __restrict__ Ahat, const __hip_bfloat16* __restrict__ Khat,
    const float* __restrict__ hsq, const float* __restrict__ ksq,
    const float* __restrict__ mask, const float* __restrict__ klen,
    float* __restrict__ stats_m, float* __restrict__ stats_z) {
  extern __shared__ char smraw[];
  char*  A_lds  = smraw;                    // 16 rows x 256B (unpadded)
  char*  K_lds  = smraw + 8192;             // 64 rows x 272B (padded)
  float* ksq_t  = (float*)(smraw + 8192 + 17408);  // 64
  float* klen_t = ksq_t + 64;               // 64
  float* hsq_t  = klen_t + 64;              // 16
  float* wm     = hsq_t + 16;               // [4][16]
  float* wz     = wm + 64;                  // [4][16]

  int c = blockIdx.z;
  int l0 = blockIdx.x * 16; int g = blockIdx.y; int n = g >> 3;
  int t = threadIdx.x; int w = t >> 6; int lane = t & 63;
  int quad = lane >> 4; int lc = lane & 15;

  { // stage A tile (16 rows x 256B)
    int row = t >> 4, seg = t & 15;
    *(int4*)(A_lds + row*256 + seg*16) =
      *(const int4*)((const char*)Ahat + (((size_t)(c*G_+g))*L_ + l0 + row)*256 + seg*16);
  }
  if (t < 16) hsq_t[t] = hsq[((size_t)(c*G_+g))*L_ + l0 + t];
  __syncthreads();

  short8 afr[4];
  #pragma unroll
  for (int kt = 0; kt < 4; kt++)
    afr[kt] = *(const short8*)(A_lds + lc*256 + kt*64 + quad*16);

  float rm[4], rz[4], hqv[4];
  #pragma unroll
  for (int i = 0; i < 4; i++) { rm[i] = -INFINITY; rz[i] = 0.0f; hqv[i] = hsq_t[quad*4 + i]; }

  #pragma unroll 1
  for (int st = 0; st < 16; st++) {
    int s0 = st*64;
    __syncthreads();
    #pragma unroll
    for (int rep = 0; rep < 4; rep++) {
      int u = t + rep*256; int row = u >> 4, seg = u & 15;
      *(int4*)(K_lds + row*272 + seg*16) =
        *(const int4*)((const char*)Khat + (((size_t)g)*S_ + s0 + row)*256 + seg*16);
    }
    if (t < 64) { ksq_t[t] = ksq[(size_t)g*S_ + s0 + t]; klen_t[t] = klen[(size_t)n*S_ + s0 + t]; }
    __syncthreads();
    short8 bfr[4];
    #pragma unroll
    for (int kt = 0; kt < 4; kt++)
      bfr[kt] = *(const short8*)(K_lds + (w*16+lc)*272 + kt*64 + quad*16);
    floatx4 acc = {0.f, 0.f, 0.f, 0.f};
    // split-bf16: hi.hi + hi.lo + lo.hi  (kt 0,1 = hi; 2,3 = lo)
    acc = MFMA16(afr[0], bfr[0], acc, 0,0,0);
    acc = MFMA16(afr[1], bfr[1], acc, 0,0,0);
    acc = MFMA16(afr[0], bfr[2], acc, 0,0,0);
    acc = MFMA16(afr[1], bfr[3], acc, 0,0,0);
    acc = MFMA16(afr[2], bfr[0], acc, 0,0,0);
    acc = MFMA16(afr[3], bfr[1], acc, 0,0,0);
    int scol = s0 + w*16 + lc;
    float kqv = ksq_t[w*16+lc];
    float klv = klen_t[w*16+lc];
    #pragma unroll
    for (int i = 0; i < 4; i++) {
      int l = l0 + quad*4 + i;
      float x = logit_rt(c, acc[i], hqv[i], kqv)
              + mask[((size_t)(n*L_ + l))*S_ + scol] + klv;
      float mn = fmaxf(rm[i], x);
      rz[i] = rz[i]*__expf(rm[i]-mn) + __expf(x - mn);
      rm[i] = mn;
    }
  }
  // butterfly merge across the 16 lanes of each row-group
  #pragma unroll
  for (int off = 1; off < 16; off <<= 1) {
    #pragma unroll
    for (int i = 0; i < 4; i++) {
      float mo = __shfl_xor(rm[i], off);
      float zo = __shfl_xor(rz[i], off);
      float mn = fmaxf(rm[i], mo);
      rz[i] = rz[i]*__expf(rm[i]-mn) + zo*__expf(mo-mn);
      rm[i] = mn;
    }
  }
  if (lc == 0) {
    #pragma unroll
    for (int i = 0; i < 4; i++) { wm[w*16 + quad*4 + i] = rm[i]; wz[w*16 + quad*4 + i] = rz[i]; }
  }
  __syncthreads();
  if (t < 16) {
    float m = wm[t], z = wz[t];
    #pragma unroll
    for (int w2 = 1; w2 < 4; w2++) {
      float mo = wm[w2*16 + t], zo = wz[w2*16 + t];
      float mn = fmaxf(m, mo);
      z = z*__expf(m - mn) + zo*__expf(mo - mn);
      m = mn;
    }
    stats_m[((size_t)(c*G_+g))*L_ + l0 + t] = m;
    stats_z[((size_t)(c*G_+g))*L_ + l0 + t] = z;
  }
}

// ---------------------------------------------------------------------------
// K3: emit pass. grid (64 ltiles, 16 g), 256 thr. All 6 codes fused per block
// so key tile is staged once per s-tile. Dyn LDS = 44,032 B.
// ---------------------------------------------------------------------------
__global__ __launch_bounds__(256) void k_emit(
    const __hip_bfloat16* __restrict__ Ahat, const __hip_bfloat16* __restrict__ Khat,
    const float* __restrict__ hsq, const float* __restrict__ ksq,
    const float* __restrict__ mask, const float* __restrict__ klen,
    const float* __restrict__ pi_t, const float* __restrict__ stats_m,
    const float* __restrict__ stats_z, float* __restrict__ out) {
  extern __shared__ char smraw[];
  char*   A6     = smraw;                    // 6 x 16 rows x 256B
  char*   K_lds  = smraw + 24576;            // 64 x 272B
  float*  ksq_t  = (float*)(smraw + 24576 + 17408);
  float*  klen_t = ksq_t + 64;
  float4* cst    = (float4*)(klen_t + 64);   // [6][16]: {m, pi/Z, hsq, 0}

  int l0 = blockIdx.x * 16; int g = blockIdx.y; int n = g >> 3;
  int t = threadIdx.x; int w = t >> 6; int lane = t & 63;
  int quad = lane >> 4; int lc = lane & 15;

  #pragma unroll
  for (int rep = 0; rep < 6; rep++) {
    int u = t + rep*256; int cc = u >> 8; int rem = u & 255;
    int row = rem >> 4; int seg = rem & 15;
    *(int4*)(A6 + cc*4096 + row*256 + seg*16) =
      *(const int4*)((const char*)Ahat + (((size_t)(cc*G_+g))*L_ + l0 + row)*256 + seg*16);
  }
  if (t < 96) {
    int cc = t >> 4; int row = t & 15;
    size_t idx = ((size_t)(cc*G_+g))*L_ + l0 + row;
    float m = stats_m[idx], z = stats_z[idx];
    float p = pi_t[idx], hq = hsq[idx];
    cst[cc*16 + row] = make_float4(m, p / z, hq, 0.0f);
  }
  __syncthreads();

  short8 a6f[6][4];
  #pragma unroll
  for (int cc = 0; cc < 6; cc++)
    #pragma unroll
    for (int kt = 0; kt < 4; kt++)
      a6f[cc][kt] = *(const short8*)(A6 + cc*4096 + lc*256 + kt*64 + quad*16);

  #pragma unroll 1
  for (int st = 0; st < 16; st++) {
    int s0 = st*64;
    __syncthreads();
    #pragma unroll
    for (int rep = 0; rep < 4; rep++) {
      int u = t + rep*256; int row = u >> 4, seg = u & 15;
      *(int4*)(K_lds + row*272 + seg*16) =
        *(const int4*)((const char*)Khat + (((size_t)g)*S_ + s0 + row)*256 + seg*16);
    }
    if (t < 64) { ksq_t[t] = ksq[(size_t)g*S_ + s0 + t]; klen_t[t] = klen[(size_t)n*S_ + s0 + t]; }
    __syncthreads();
    short8 bfr[4];
    #pragma unroll
    for (int kt = 0; kt < 4; kt++)
      bfr[kt] = *(const short8*)(K_lds + (w*16+lc)*272 + kt*64 + quad*16);
    int scol = s0 + w*16 + lc;
    float kqv = ksq_t[w*16+lc];
    float klv = klen_t[w*16+lc];
    float mv[4];
    #pragma unroll
    for (int i = 0; i < 4; i++)
      mv[i] = mask[((size_t)(n*L_ + l0 + quad*4 + i))*S_ + scol] + klv;
    float out4[4] = {0.f, 0.f, 0.f, 0.f};
    #pragma unroll
    for (int c = 0; c < 6; c++) {
      floatx4 acc = {0.f, 0.f, 0.f, 0.f};
      acc = MFMA16(a6f[c][0], bfr[0], acc, 0,0,0);
      acc = MFMA16(a6f[c][1], bfr[1], acc, 0,0,0);
      acc = MFMA16(a6f[c][0], bfr[2], acc, 0,0,0);
      acc = MFMA16(a6f[c][1], bfr[3], acc, 0,0,0);
      acc = MFMA16(a6f[c][2], bfr[0], acc, 0,0,0);
      acc = MFMA16(a6f[c][3], bfr[1], acc, 0,0,0);
      #pragma unroll
      for (int i = 0; i < 4; i++) {
        float4 cs = cst[c*16 + quad*4 + i];
        float x = logit_rt(c, acc[i], cs.z, kqv) + mv[i];
        out4[i] += cs.y * __expf(x - cs.x);
      }
    }
    #pragma unroll
    for (int i = 0; i < 4; i++)
      out[(((size_t)g)*L_ + l0 + quad*4 + i)*S_ + scol] = out4[i];
  }
}

// ---------------------------------------------------------------------------
extern "C" void kernel_launch(void* const* d_in, const int* in_sizes, int n_in,
                              void* d_out, int out_size, void* d_ws, size_t ws_size,
                              hipStream_t stream) {
  (void)in_sizes; (void)n_in; (void)out_size; (void)ws_size;
  const float* q    = (const float*)d_in[0];
  const float* key  = (const float*)d_in[1];
  const float* mask = (const float*)d_in[2];
  const float* klen = (const float*)d_in[3];
  const float* M    = (const float*)d_in[4];
  const float* C    = (const float*)d_in[5];
  char* ws = (char*)d_ws;
  __hip_bfloat16* Ahat = (__hip_bfloat16*)(ws + AHAT_OFF);
  __hip_bfloat16* Khat = (__hip_bfloat16*)(ws + KHAT_OFF);
  float* pi_t    = (float*)(ws + PI_OFF);
  float* hsq     = (float*)(ws + HSQ_OFF);
  float* ksq     = (float*)(ws + KSQ_OFF);
  float* stats_m = (float*)(ws + SM_OFF);
  float* stats_z = (float*)(ws + SZ_OFF);
  float* out = (float*)d_out;

  k_prep_a<<<512, 256, 59360, stream>>>(q, M, C, Ahat, pi_t, hsq);
  k_prep_k<<<4096, 256, 0, stream>>>(key, Khat, ksq);
  k_stats<<<dim3(64, 16, 6), 256, 26688, stream>>>(Ahat, Khat, hsq, ksq, mask, klen,
                                                   stats_m, stats_z);
  k_emit<<<dim3(64, 16), 256, 44032, stream>>>(Ahat, Khat, hsq, ksq, mask, klen,
                                               pi_t, stats_m, stats_z, out);
}

// Round 2
// 280.839 us; speedup vs baseline: 1.3598x; 1.3598x over previous
//
#include <hip/hip_runtime.h>
#include <hip/hip_bf16.h>
#include <math.h>

// Problem constants
#define N_  2
#define H_  8
#define G_  16      // N_*H_
#define L_  1024
#define S_  1024
#define E_  64
#define NC_ 6

typedef __attribute__((ext_vector_type(4))) float floatx4;
typedef __attribute__((ext_vector_type(8))) short short8;

#define MFMA16 __builtin_amdgcn_mfma_f32_16x16x32_bf16

// ---------------- workspace layout (bytes) ----------------
#define AHAT_OFF   0
#define AHAT_BYTES (NC_*G_*L_*128*2)          // 25,165,824
#define KHAT_OFF   (AHAT_OFF + AHAT_BYTES)
#define KHAT_BYTES (G_*S_*128*2)              //  4,194,304
#define PI_OFF     (KHAT_OFF + KHAT_BYTES)    // pi_t: [c][g][l] f32
#define PI_BYTES   (NC_*G_*L_*4)
#define HSQ_OFF    (PI_OFF + PI_BYTES)        // hsq: [c][g][l] f32
#define HSQ_BYTES  (NC_*G_*L_*4)
#define KSQ_OFF    (HSQ_OFF + HSQ_BYTES)      // ksq: [g][s] f32
#define KSQ_BYTES  (G_*S_*4)

// Logit for code c (compile-time constant after unroll). Must be identical
// between stats and emit sweeps (it is: same inline code, same inputs).
__device__ __forceinline__ float logit_rt(int c, float d, float hq, float kq) {
  if (c == 0) return d;                               // L
  if (c == 3) { float tt = d + 1.0f; return tt*tt; }  // Y
  float ns = hq + kq - 2.0f*d;
  if (c == 1) return -__logf(1.0f + ns);              // O
  if (c == 2) return -ns;                             // P
  if (c == 4) return __expf(-0.5f*ns);                // R
  return __cosf(ns) * __expf(-ns);                    // W
}

// ---------------------------------------------------------------------------
// K1a: per (n,h,l-chunk of 32): pi (softmax over 6), htilde=tanh(q@C[c,h])
// split to bf16 hi/lo, and |htilde|^2.  (unchanged from round 1)
// ---------------------------------------------------------------------------
__global__ __launch_bounds__(256) void k_prep_a(
    const float* __restrict__ q, const float* __restrict__ M,
    const float* __restrict__ C, __hip_bfloat16* __restrict__ Ahat,
    float* __restrict__ pi_t, float* __restrict__ hsq) {
  extern __shared__ char smraw[];
  float* qs    = (float*)smraw;          // [32][65]
  float* Cs    = qs + 32*65;             // [3][4104]
  float* hsq_s = Cs + 3*4104;            // [6][32]
  float* pm    = hsq_s + 6*32;           // [32][8]

  int b  = blockIdx.x;
  int n  = b >> 8; int h = (b >> 5) & 7; int lc = b & 31;
  int l0 = lc * 32; int g = n*8 + h;
  int t  = threadIdx.x;

  if (t < 192) hsq_s[t] = 0.0f;
  {
    int u = t;
    #pragma unroll
    for (int rep = 0; rep < 2; rep++, u += 256) {
      int row = u >> 4, seg = u & 15;
      float4 v = *(const float4*)(q + (((size_t)(n*L_ + l0 + row))*H_ + h)*E_ + seg*4);
      float* dst = qs + row*65 + seg*4;
      dst[0]=v.x; dst[1]=v.y; dst[2]=v.z; dst[3]=v.w;
    }
  }
  for (int gc = 0; gc < 2; gc++) {
    __syncthreads();
    for (int u = t; u < 3072; u += 256) {
      int cc = u >> 10; int rem = u & 1023; int e = rem >> 4; int seg = rem & 15;
      float4 v = *(const float4*)(C + (((size_t)((gc*3+cc)*8 + h))*64 + e)*64 + seg*4);
      float* dst = Cs + cc*4104 + e*64 + seg*4;
      dst[0]=v.x; dst[1]=v.y; dst[2]=v.z; dst[3]=v.w;
    }
    __syncthreads();
    if (t < 192) {
      int cc = t >> 6; int tt = t & 63; int lg = tt >> 3; int fg = tt & 7;
      int c = gc*3 + cc;
      float acc[4][8];
      #pragma unroll
      for (int i = 0; i < 4; i++)
        #pragma unroll
        for (int j = 0; j < 8; j++) acc[i][j] = 0.0f;
      for (int e = 0; e < 64; e++) {
        float c8[8];
        #pragma unroll
        for (int j = 0; j < 8; j++) c8[j] = Cs[cc*4104 + e*64 + fg*8 + j];
        #pragma unroll
        for (int i = 0; i < 4; i++) {
          float qv = qs[(lg*4+i)*65 + e];
          #pragma unroll
          for (int j = 0; j < 8; j++) acc[i][j] = fmaf(qv, c8[j], acc[i][j]);
        }
      }
      #pragma unroll
      for (int i = 0; i < 4; i++) {
        int l = l0 + lg*4 + i;
        size_t rowb = (((size_t)(c*G_ + g))*L_ + l) * 128;
        float ss = 0.0f;
        #pragma unroll
        for (int j = 0; j < 8; j++) {
          float hv = tanhf(acc[i][j]);
          ss += hv*hv;
          __hip_bfloat16 hi = __float2bfloat16(hv);
          __hip_bfloat16 lo = __float2bfloat16(hv - __bfloat162float(hi));
          Ahat[rowb + fg*8 + j]      = hi;
          Ahat[rowb + 64 + fg*8 + j] = lo;
        }
        atomicAdd(&hsq_s[c*32 + lg*4 + i], ss);
      }
    }
  }
  if (t < 192) {
    int k = t >> 5; int l = t & 31;
    float p = 0.0f;
    for (int e = 0; e < 64; e++) p += qs[l*65 + e] * M[(h*64 + e)*6 + k];
    pm[l*8 + k] = p;
  }
  __syncthreads();
  if (t < 192) {
    int k = t >> 5; int l = t & 31;
    float mx = pm[l*8+0];
    #pragma unroll
    for (int kk = 1; kk < 6; kk++) mx = fmaxf(mx, pm[l*8+kk]);
    float den = 0.0f;
    #pragma unroll
    for (int kk = 0; kk < 6; kk++) den += __expf(pm[l*8+kk] - mx);
    float pv = __expf(pm[l*8+k] - mx) / den;
    size_t idx = ((size_t)(k*G_ + g))*L_ + l0 + l;
    pi_t[idx] = pv;
    hsq[idx]  = hsq_s[k*32 + l];
  }
}

// ---------------------------------------------------------------------------
// K1b: key split hi/lo + ksq. (unchanged)
// ---------------------------------------------------------------------------
__global__ __launch_bounds__(256) void k_prep_k(
    const float* __restrict__ key, __hip_bfloat16* __restrict__ Khat,
    float* __restrict__ ksq) {
  int t = threadIdx.x; int wv = t >> 6; int lane = t & 63;
  int r = blockIdx.x*4 + wv;
  int g = r >> 10; int s = r & 1023; int n = g >> 3; int h = g & 7;
  float v = key[(((size_t)(n*S_ + s))*H_ + h)*E_ + lane];
  __hip_bfloat16 hi = __float2bfloat16(v);
  __hip_bfloat16 lo = __float2bfloat16(v - __bfloat162float(hi));
  size_t base = ((size_t)g*S_ + s)*128;
  Khat[base + lane]      = hi;
  Khat[base + 64 + lane] = lo;
  float sq = v*v;
  #pragma unroll
  for (int off = 32; off; off >>= 1) sq += __shfl_xor(sq, off);
  if (lane == 0) ksq[(size_t)g*S_ + s] = sq;
}

// ---------------------------------------------------------------------------
// K2: FUSED stats + emit. grid (64 ltiles, 16 g), 256 thr (4 waves).
// Block owns 16 l-rows x all 6 codes. Sweep 1: online (m,Z) per code.
// Sweep 2: emit sum_c pi_c/Z_c * exp(x_c - m_c).
// A-frags for all 6 codes live in VGPRs across both sweeps.
// ---------------------------------------------------------------------------
#define LDS_A6    0                      // 6*16*256        = 24576
#define LDS_K     24576                  // 64*272          = 17408
#define LDS_KSQ   41984                  // 64 f            = 256
#define LDS_KLEN  42240                  // 64 f            = 256
#define LDS_CST   42496                  // 6*16 float2     = 768
#define LDS_WMZ   43264                  // 4*96*2 f        = 3072
#define LDS_HSQ   46336                  // 96 f            = 384
#define LDS_PI    46720                  // 96 f            = 384
#define LDS_TOTAL 47104

__global__ __launch_bounds__(256, 2) void k_main(
    const __hip_bfloat16* __restrict__ Ahat, const __hip_bfloat16* __restrict__ Khat,
    const float* __restrict__ hsq, const float* __restrict__ ksq,
    const float* __restrict__ mask, const float* __restrict__ klen,
    const float* __restrict__ pi_t, float* __restrict__ out) {
  extern __shared__ char smraw[];
  char*   A6     = smraw + LDS_A6;
  char*   K_lds  = smraw + LDS_K;
  float*  ksq_t  = (float*)(smraw + LDS_KSQ);
  float*  klen_t = (float*)(smraw + LDS_KLEN);
  float2* cst    = (float2*)(smraw + LDS_CST);
  float*  wmz    = (float*)(smraw + LDS_WMZ);    // [w][ c*16+row ] m, +384 z
  float*  hsq_s  = (float*)(smraw + LDS_HSQ);
  float*  pi_s   = (float*)(smraw + LDS_PI);

  int l0 = blockIdx.x * 16; int g = blockIdx.y; int n = g >> 3;
  int t = threadIdx.x; int w = t >> 6; int lane = t & 63;
  int quad = lane >> 4; int lc = lane & 15;

  // ---- stage A tiles for all 6 codes + per-row constants ----
  #pragma unroll
  for (int rep = 0; rep < 6; rep++) {
    int u = t + rep*256; int cc = u >> 8; int rem = u & 255;
    int row = rem >> 4; int seg = rem & 15;
    *(int4*)(A6 + cc*4096 + row*256 + seg*16) =
      *(const int4*)((const char*)Ahat + (((size_t)(cc*G_+g))*L_ + l0 + row)*256 + seg*16);
  }
  if (t < 96) {
    int cc = t >> 4; int row = t & 15;
    size_t idx = ((size_t)(cc*G_+g))*L_ + l0 + row;
    hsq_s[t] = hsq[idx];
    pi_s[t]  = pi_t[idx];
  }
  __syncthreads();

  short8 a6f[6][4];
  float  hqv[6][4];
  #pragma unroll
  for (int cc = 0; cc < 6; cc++) {
    #pragma unroll
    for (int kt = 0; kt < 4; kt++)
      a6f[cc][kt] = *(const short8*)(A6 + cc*4096 + lc*256 + kt*64 + quad*16);
    #pragma unroll
    for (int i = 0; i < 4; i++) hqv[cc][i] = hsq_s[cc*16 + quad*4 + i];
  }

  float rm[6][4], rz[6][4];
  #pragma unroll
  for (int c = 0; c < 6; c++)
    #pragma unroll
    for (int i = 0; i < 4; i++) { rm[c][i] = -INFINITY; rz[c][i] = 0.0f; }

  // ================= sweep 1: stats =================
  #pragma unroll 1
  for (int st = 0; st < 16; st++) {
    int s0 = st*64;
    __syncthreads();
    #pragma unroll
    for (int rep = 0; rep < 4; rep++) {
      int u = t + rep*256; int row = u >> 4, seg = u & 15;
      *(int4*)(K_lds + row*272 + seg*16) =
        *(const int4*)((const char*)Khat + (((size_t)g)*S_ + s0 + row)*256 + seg*16);
    }
    if (t < 64) { ksq_t[t] = ksq[(size_t)g*S_ + s0 + t]; klen_t[t] = klen[(size_t)n*S_ + s0 + t]; }
    __syncthreads();
    short8 bfr[4];
    #pragma unroll
    for (int kt = 0; kt < 4; kt++)
      bfr[kt] = *(const short8*)(K_lds + (w*16+lc)*272 + kt*64 + quad*16);
    int scol = s0 + w*16 + lc;
    float kqv = ksq_t[w*16+lc];
    float klv = klen_t[w*16+lc];
    float mv[4];
    #pragma unroll
    for (int i = 0; i < 4; i++)
      mv[i] = mask[((size_t)(n*L_ + l0 + quad*4 + i))*S_ + scol] + klv;
    #pragma unroll
    for (int c = 0; c < 6; c++) {
      floatx4 acc = {0.f, 0.f, 0.f, 0.f};
      acc = MFMA16(a6f[c][0], bfr[0], acc, 0,0,0);
      acc = MFMA16(a6f[c][1], bfr[1], acc, 0,0,0);
      acc = MFMA16(a6f[c][0], bfr[2], acc, 0,0,0);
      acc = MFMA16(a6f[c][1], bfr[3], acc, 0,0,0);
      acc = MFMA16(a6f[c][2], bfr[0], acc, 0,0,0);
      acc = MFMA16(a6f[c][3], bfr[1], acc, 0,0,0);
      #pragma unroll
      for (int i = 0; i < 4; i++) {
        float x = logit_rt(c, acc[i], hqv[c][i], kqv) + mv[i];
        // 1-exp online update
        float mn = fmaxf(rm[c][i], x);
        float e  = __expf(fminf(rm[c][i], x) - mn);
        rz[c][i] = (x > rm[c][i]) ? fmaf(rz[c][i], e, 1.0f) : (rz[c][i] + e);
        rm[c][i] = mn;
      }
    }
  }
  // ---- merge 16 lanes (1-exp trick; rm finite after 16 tiles) ----
  #pragma unroll
  for (int c = 0; c < 6; c++)
    #pragma unroll
    for (int off = 1; off < 16; off <<= 1)
      #pragma unroll
      for (int i = 0; i < 4; i++) {
        float mo = __shfl_xor(rm[c][i], off);
        float zo = __shfl_xor(rz[c][i], off);
        float mn = fmaxf(rm[c][i], mo);
        float e  = __expf(fminf(rm[c][i], mo) - mn);
        rz[c][i] = (mo > rm[c][i]) ? fmaf(rz[c][i], e, zo) : fmaf(zo, e, rz[c][i]);
        rm[c][i] = mn;
      }
  if (lc == 0) {
    #pragma unroll
    for (int c = 0; c < 6; c++)
      #pragma unroll
      for (int i = 0; i < 4; i++) {
        wmz[w*96 + c*16 + quad*4 + i]       = rm[c][i];
        wmz[384 + w*96 + c*16 + quad*4 + i] = rz[c][i];
      }
  }
  __syncthreads();
  if (t < 96) {
    float m = wmz[t], z = wmz[384 + t];
    #pragma unroll
    for (int w2 = 1; w2 < 4; w2++) {
      float mo = wmz[w2*96 + t], zo = wmz[384 + w2*96 + t];
      float mn = fmaxf(m, mo);
      float e  = __expf(fminf(m, mo) - mn);
      z = (mo > m) ? fmaf(z, e, zo) : fmaf(zo, e, z);
      m = mn;
    }
    cst[t] = make_float2(m, pi_s[t] / z);
  }
  __syncthreads();

  float cm[6][4], ca[6][4];
  #pragma unroll
  for (int c = 0; c < 6; c++)
    #pragma unroll
    for (int i = 0; i < 4; i++) {
      float2 v = cst[c*16 + quad*4 + i];
      cm[c][i] = v.x; ca[c][i] = v.y;
    }

  // ================= sweep 2: emit =================
  #pragma unroll 1
  for (int st = 0; st < 16; st++) {
    int s0 = st*64;
    __syncthreads();
    #pragma unroll
    for (int rep = 0; rep < 4; rep++) {
      int u = t + rep*256; int row = u >> 4, seg = u & 15;
      *(int4*)(K_lds + row*272 + seg*16) =
        *(const int4*)((const char*)Khat + (((size_t)g)*S_ + s0 + row)*256 + seg*16);
    }
    if (t < 64) { ksq_t[t] = ksq[(size_t)g*S_ + s0 + t]; klen_t[t] = klen[(size_t)n*S_ + s0 + t]; }
    __syncthreads();
    short8 bfr[4];
    #pragma unroll
    for (int kt = 0; kt < 4; kt++)
      bfr[kt] = *(const short8*)(K_lds + (w*16+lc)*272 + kt*64 + quad*16);
    int scol = s0 + w*16 + lc;
    float kqv = ksq_t[w*16+lc];
    float klv = klen_t[w*16+lc];
    float mv[4];
    #pragma unroll
    for (int i = 0; i < 4; i++)
      mv[i] = mask[((size_t)(n*L_ + l0 + quad*4 + i))*S_ + scol] + klv;
    float out4[4] = {0.f, 0.f, 0.f, 0.f};
    #pragma unroll
    for (int c = 0; c < 6; c++) {
      floatx4 acc = {0.f, 0.f, 0.f, 0.f};
      acc = MFMA16(a6f[c][0], bfr[0], acc, 0,0,0);
      acc = MFMA16(a6f[c][1], bfr[1], acc, 0,0,0);
      acc = MFMA16(a6f[c][0], bfr[2], acc, 0,0,0);
      acc = MFMA16(a6f[c][1], bfr[3], acc, 0,0,0);
      acc = MFMA16(a6f[c][2], bfr[0], acc, 0,0,0);
      acc = MFMA16(a6f[c][3], bfr[1], acc, 0,0,0);
      #pragma unroll
      for (int i = 0; i < 4; i++) {
        float x = logit_rt(c, acc[i], hqv[c][i], kqv) + mv[i];
        out4[i] += ca[c][i] * __expf(x - cm[c][i]);
      }
    }
    #pragma unroll
    for (int i = 0; i < 4; i++)
      out[(((size_t)g)*L_ + l0 + quad*4 + i)*S_ + scol] = out4[i];
  }
}

// ---------------------------------------------------------------------------
extern "C" void kernel_launch(void* const* d_in, const int* in_sizes, int n_in,
                              void* d_out, int out_size, void* d_ws, size_t ws_size,
                              hipStream_t stream) {
  (void)in_sizes; (void)n_in; (void)out_size; (void)ws_size;
  const float* q    = (const float*)d_in[0];
  const float* key  = (const float*)d_in[1];
  const float* mask = (const float*)d_in[2];
  const float* klen = (const float*)d_in[3];
  const float* M    = (const float*)d_in[4];
  const float* C    = (const float*)d_in[5];
  char* ws = (char*)d_ws;
  __hip_bfloat16* Ahat = (__hip_bfloat16*)(ws + AHAT_OFF);
  __hip_bfloat16* Khat = (__hip_bfloat16*)(ws + KHAT_OFF);
  float* pi_t    = (float*)(ws + PI_OFF);
  float* hsq     = (float*)(ws + HSQ_OFF);
  float* ksq     = (float*)(ws + KSQ_OFF);
  float* out = (float*)d_out;

  k_prep_a<<<512, 256, 59360, stream>>>(q, M, C, Ahat, pi_t, hsq);
  k_prep_k<<<4096, 256, 0, stream>>>(key, Khat, ksq);
  k_main<<<dim3(64, 16), 256, LDS_TOTAL, stream>>>(Ahat, Khat, hsq, ksq, mask, klen,
                                                   pi_t, out);
}